// Round 1
// baseline (214.368 us; speedup 1.0000x reference)
//
#include <hip/hip_runtime.h>
#include <stdint.h>

// Problem: B=4096, I=256, O=256, G=32
// out[b,j] = bias[j] + sum_i [ mask*scale_base[i,j]*silu(x[b,i])
//            + mask*scale_fft[i,j]* sum_k ( cos(k*x)*fc0[j,i,k] + sin(k*x)*fc1[j,i,k] ) ]
// Restructured as GEMM: M=4096, N=256, K=256*65=16640, bf16 MFMA 16x16x32.

#define I_DIM 256
#define O_DIM 256
#define G_DIM 32

#define BM 128
#define BN 64
#define KSPLIT 4
#define I_PER_CHUNK 64          // 256 / KSPLIT i's per K-chunk

#define APITCH 72               // shorts per A row (64 + 8 pad -> breaks 128B stride)
#define BPITCH 72

typedef short s8v __attribute__((ext_vector_type(8)));   // 8 bf16 (4 VGPRs)
typedef float f4v __attribute__((ext_vector_type(4)));   // 4 f32 acc

__device__ __forceinline__ uint32_t pack2bf16(float a, float b) {
  uint32_t ua = __builtin_bit_cast(uint32_t, a);
  uint32_t ub = __builtin_bit_cast(uint32_t, b);
  ua += 0x7FFFu + ((ua >> 16) & 1u);     // RNE
  ub += 0x7FFFu + ((ub >> 16) & 1u);
  return (ua >> 16) | (ub & 0xFFFF0000u);
}

__device__ __forceinline__ float silu_f(float v) {
  return v / (1.0f + __expf(-v));
}

__global__ __launch_bounds__(256, 2) void kan_fft_kernel(
    const float* __restrict__ x,          // (4096, 256)
    const float* __restrict__ fc,         // (2, 256, 256, 32)
    const float* __restrict__ bias,       // (256,)
    const float* __restrict__ mask,       // (256, 256)
    const float* __restrict__ scale_base, // (256, 256)
    const float* __restrict__ scale_fft,  // (256, 256)
    float* __restrict__ out)              // (4096, 256) f32, pre-zeroed
{
  __shared__ short A_lds[BM * APITCH];    // [m][t]  t in [0,64)
  __shared__ short B_lds[BN * BPITCH];    // [n][t]

  const int tid = threadIdx.x;
  const int bx  = blockIdx.x;
  const int bm  = bx & 31;                // 32 M-tiles (low bits -> same fc slice shared across XCDs)
  const int bn  = (bx >> 5) & 3;          // 4 N-tiles
  const int kc  = bx >> 7;                // 4 K-chunks

  const int i0   = kc * I_PER_CHUNK;
  const int lane = tid & 63;
  const int wave = tid >> 6;
  const int wm   = wave & 1;              // 2x2 wave grid: 64 rows x 32 cols each
  const int wn   = wave >> 1;
  const int l15  = lane & 15;
  const int kgrp = (lane >> 4) * 8;

  f4v acc[4][2];
  #pragma unroll
  for (int a = 0; a < 4; ++a)
    #pragma unroll
    for (int b = 0; b < 2; ++b)
      acc[a][b] = (f4v){0.f, 0.f, 0.f, 0.f};

  // staging roles
  const int row  = tid;                   // A-staging: threads 0..127, one M-row each
  const int tid2 = tid - 128;             // B-staging: threads 128..255
  const int jloc = tid2 >> 1;             // 64 j's
  const int half = tid2 & 1;              // 0 = fc0(cos), 1 = fc1(sin)
  const int jg   = bn * BN + jloc;

  for (int it = 0; it < I_PER_CHUNK + 1; ++it) {
    __syncthreads();                      // previous MFMA reads done before overwrite

    if (it < I_PER_CHUNK) {
      // ---------------- fourier K-tile: i fixed, t = [cos 1..32 | sin 1..32]
      const int i = i0 + it;
      if (tid < BM) {
        float xv = x[(size_t)(bm * BM + row) * I_DIM + i];
        float s1, c1;
        __sincosf(xv, &s1, &c1);
        uint32_t cbuf[16], sbuf[16];
        float ca = c1, sa = s1;           // cos(1x), sin(1x)
        #pragma unroll
        for (int p = 0; p < 16; ++p) {    // emit k = 2p+1, 2p+2
          float cb = ca * c1 - sa * s1;
          float sb = sa * c1 + ca * s1;
          cbuf[p] = pack2bf16(ca, cb);
          sbuf[p] = pack2bf16(sa, sb);
          ca = cb * c1 - sb * s1;
          sa = sb * c1 + cb * s1;
        }
        uint32_t* Ar = (uint32_t*)&A_lds[row * APITCH];
        #pragma unroll
        for (int q = 0; q < 4; ++q)
          ((uint4*)Ar)[q] = make_uint4(cbuf[4*q], cbuf[4*q+1], cbuf[4*q+2], cbuf[4*q+3]);
        #pragma unroll
        for (int q = 0; q < 4; ++q)
          ((uint4*)(Ar + 16))[q] = make_uint4(sbuf[4*q], sbuf[4*q+1], sbuf[4*q+2], sbuf[4*q+3]);
      } else {
        const size_t ij = (size_t)i * O_DIM + jg;
        const float sf  = scale_fft[ij] * mask[ij];
        const float* src = fc + (size_t)half * (O_DIM * I_DIM * G_DIM)
                              + ((size_t)jg * I_DIM + i) * G_DIM;   // 32 consecutive floats
        uint32_t wbuf[16];
        #pragma unroll
        for (int q = 0; q < 8; ++q) {
          float4 v = ((const float4*)src)[q];
          wbuf[2*q]   = pack2bf16(v.x * sf, v.y * sf);
          wbuf[2*q+1] = pack2bf16(v.z * sf, v.w * sf);
        }
        uint32_t* Br = (uint32_t*)&B_lds[jloc * BPITCH + half * 32];
        #pragma unroll
        for (int q = 0; q < 4; ++q)
          ((uint4*)Br)[q] = make_uint4(wbuf[4*q], wbuf[4*q+1], wbuf[4*q+2], wbuf[4*q+3]);
      }
    } else {
      // ---------------- base K-tile: t = i_local in [0,64), feature = silu(x)
      if (tid < BM) {
        const float* xr = x + (size_t)(bm * BM + row) * I_DIM + i0;
        uint32_t fbuf[32];
        #pragma unroll
        for (int q = 0; q < 16; ++q) {
          float4 v = ((const float4*)xr)[q];
          fbuf[2*q]   = pack2bf16(silu_f(v.x), silu_f(v.y));
          fbuf[2*q+1] = pack2bf16(silu_f(v.z), silu_f(v.w));
        }
        uint32_t* Ar = (uint32_t*)&A_lds[row * APITCH];
        #pragma unroll
        for (int q = 0; q < 8; ++q)
          ((uint4*)Ar)[q] = make_uint4(fbuf[4*q], fbuf[4*q+1], fbuf[4*q+2], fbuf[4*q+3]);
      } else {
        uint32_t wbuf[16];
        #pragma unroll
        for (int p = 0; p < 16; ++p) {
          const int ia = i0 + half * 32 + 2 * p;
          const size_t o0 = (size_t)ia * O_DIM + jg;
          const size_t o1 = o0 + O_DIM;
          float wa = scale_base[o0] * mask[o0];
          float wb = scale_base[o1] * mask[o1];
          wbuf[p] = pack2bf16(wa, wb);
        }
        uint32_t* Br = (uint32_t*)&B_lds[jloc * BPITCH + half * 32];
        #pragma unroll
        for (int q = 0; q < 4; ++q)
          ((uint4*)Br)[q] = make_uint4(wbuf[4*q], wbuf[4*q+1], wbuf[4*q+2], wbuf[4*q+3]);
      }
    }

    __syncthreads();

    // ---------------- MFMA over this 64-wide K-tile (2 k-steps of 32)
    #pragma unroll
    for (int ks = 0; ks < 2; ++ks) {
      s8v a[4], b[2];
      #pragma unroll
      for (int tm = 0; tm < 4; ++tm)
        a[tm] = *(const s8v*)&A_lds[(wm * 64 + tm * 16 + l15) * APITCH + ks * 32 + kgrp];
      #pragma unroll
      for (int tn = 0; tn < 2; ++tn)
        b[tn] = *(const s8v*)&B_lds[(wn * 32 + tn * 16 + l15) * BPITCH + ks * 32 + kgrp];
      #pragma unroll
      for (int tm = 0; tm < 4; ++tm)
        #pragma unroll
        for (int tn = 0; tn < 2; ++tn)
          acc[tm][tn] = __builtin_amdgcn_mfma_f32_16x16x32_bf16(a[tm], b[tn], acc[tm][tn], 0, 0, 0);
    }
  }

  // ---------------- epilogue: C/D layout col=lane&15, row=quad*4+reg
  const int quad = lane >> 4;
  #pragma unroll
  for (int tm = 0; tm < 4; ++tm) {
    #pragma unroll
    for (int tn = 0; tn < 2; ++tn) {
      const int n_g = bn * BN + wn * 32 + tn * 16 + l15;
      f4v v = acc[tm][tn];
      #pragma unroll
      for (int r = 0; r < 4; ++r) {
        const int m_g = bm * BM + wm * 64 + tm * 16 + quad * 4 + r;
        float val = v[r];
        if (kc == 0) val += bias[n_g];           // bias added exactly once per output
        atomicAdd(&out[(size_t)m_g * O_DIM + n_g], val);
      }
    }
  }
}

extern "C" void kernel_launch(void* const* d_in, const int* in_sizes, int n_in,
                              void* d_out, int out_size, void* d_ws, size_t ws_size,
                              hipStream_t stream) {
  const float* x          = (const float*)d_in[0];
  const float* fc         = (const float*)d_in[1];
  const float* bias       = (const float*)d_in[2];
  const float* mask       = (const float*)d_in[3];
  const float* scale_base = (const float*)d_in[4];
  const float* scale_fft  = (const float*)d_in[5];
  float* out = (float*)d_out;

  // split-K accumulates via atomics -> zero the (0xAA-poisoned) output first
  hipMemsetAsync(d_out, 0, (size_t)out_size * sizeof(float), stream);

  // grid: 32 M-tiles x 4 N-tiles x 4 K-chunks = 512 blocks (2 per CU)
  kan_fft_kernel<<<dim3(512), dim3(256), 0, stream>>>(
      x, fc, bias, mask, scale_base, scale_fft, out);
}

// Round 2
// 201.336 us; speedup vs baseline: 1.0647x; 1.0647x over previous
//
#include <hip/hip_runtime.h>
#include <stdint.h>

// out[b,j] = bias[j] + sum_i [ mask*scale_base[i,j]*silu(x[b,i])
//            + mask*scale_fft[i,j]* sum_k ( cos(k*x)*fc0[j,i,k] + sin(k*x)*fc1[j,i,k] ) ]
// GEMM view: M=4096, N=256, K=256*65. bf16 MFMA 16x16x32.
// R2: 64x64 wave tiles, Chebyshev feature gen (1 FMA/elem), KSPLIT=16 (4 blk/CU),
//     bn=2 (A-redundancy 2x), kc in low grid bits for per-XCD L2 fc residency.

#define I_DIM 256
#define O_DIM 256
#define G_DIM 32

#define BM 128
#define BN 128
#define KSPLIT 16
#define ICH 16                  // i's per K-chunk
#define PITCH 72                // shorts per LDS row (64 + 8 pad; 144 B stride)

typedef short s8v __attribute__((ext_vector_type(8)));   // 8 bf16
typedef float f4v __attribute__((ext_vector_type(4)));   // 4 f32 acc

__device__ __forceinline__ uint32_t pack2bf16(float a, float b) {
  uint32_t ua = __builtin_bit_cast(uint32_t, a);
  uint32_t ub = __builtin_bit_cast(uint32_t, b);
  ua += 0x7FFFu + ((ua >> 16) & 1u);     // RNE
  ub += 0x7FFFu + ((ub >> 16) & 1u);
  return (ua >> 16) | (ub & 0xFFFF0000u);
}

__device__ __forceinline__ float silu_f(float v) {
  return v / (1.0f + __expf(-v));
}

__global__ __launch_bounds__(256, 4) void kan_fft_kernel(
    const float* __restrict__ x,          // (4096, 256)
    const float* __restrict__ fc,         // (2, 256, 256, 32)
    const float* __restrict__ bias,       // (256,)
    const float* __restrict__ mask,       // (256, 256)
    const float* __restrict__ scale_base, // (256, 256)
    const float* __restrict__ scale_fft,  // (256, 256)
    float* __restrict__ out)              // (4096, 256) f32, pre-zeroed
{
  __shared__ short A_lds[BM * PITCH];     // [m][t], t in [0,64)
  __shared__ short B_lds[BN * PITCH];     // [n][t]

  const int tid = threadIdx.x;
  const int bx  = blockIdx.x;
  const int kc  = bx & 15;                // low bits: XCD x holds kc {x, x+8} -> 4MB fc in its L2
  const int bn  = (bx >> 4) & 1;
  const int bm  = bx >> 5;
  const int i0  = kc * ICH;

  const int lane = tid & 63;
  const int wave = tid >> 6;
  const int wm   = wave & 1;              // 2x2 wave grid, 64x64 tiles
  const int wn   = wave >> 1;
  const int l15  = lane & 15;
  const int kgrp = (lane >> 4) * 8;

  f4v acc[4][4];
  #pragma unroll
  for (int a = 0; a < 4; ++a)
    #pragma unroll
    for (int b = 0; b < 4; ++b)
      acc[a][b] = (f4v){0.f, 0.f, 0.f, 0.f};

  // staging: thread pair (row, half). Every thread stages one A piece and one B piece.
  const int row  = tid >> 1;              // 0..127
  const int half = tid & 1;               // A: 0=cos,1=sin ; B: fc0/fc1
  const int mg   = bm * BM + row;
  const int jg   = bn * BN + row;

  const float* xrow   = x + (size_t)mg * I_DIM + i0;       // 16 floats = 1 cache line, L1-hot
  const float* fcbase = fc + (size_t)half * (O_DIM * I_DIM * G_DIM)
                           + ((size_t)jg * I_DIM + i0) * G_DIM;
  uint32_t* Arow = (uint32_t*)&A_lds[row * PITCH + half * 32];
  uint32_t* Brow = (uint32_t*)&B_lds[row * PITCH + half * 32];

  for (int it = 0; it < ICH; ++it) {
    __syncthreads();                      // prior MFMA reads done before overwrite

    // ---- A: Chebyshev recurrence, f_{k+1} = 2c*f_k - f_{k-1}; half=0 cos, half=1 sin
    {
      const float xv = xrow[it];
      float s, c;
      __sincosf(xv, &s, &c);
      const float m2 = 2.f * c;
      float f0 = half ? s : c;                       // k=1
      float f1 = m2 * f0 - (half ? 0.f : 1.f);       // k=2
      uint32_t fb[16];
      fb[0] = pack2bf16(f0, f1);
      #pragma unroll
      for (int p = 1; p < 16; ++p) {
        float f2 = m2 * f1 - f0;
        float f3 = m2 * f2 - f1;
        fb[p] = pack2bf16(f2, f3);
        f0 = f2; f1 = f3;
      }
      ((uint4*)Arow)[0] = make_uint4(fb[0],  fb[1],  fb[2],  fb[3]);
      ((uint4*)Arow)[1] = make_uint4(fb[4],  fb[5],  fb[6],  fb[7]);
      ((uint4*)Arow)[2] = make_uint4(fb[8],  fb[9],  fb[10], fb[11]);
      ((uint4*)Arow)[3] = make_uint4(fb[12], fb[13], fb[14], fb[15]);
    }

    // ---- B: 32 contiguous fc floats * (scale_fft*mask)
    {
      const int i = i0 + it;
      const size_t ij = (size_t)i * O_DIM + jg;
      const float sf  = scale_fft[ij] * mask[ij];
      const float* src = fcbase + it * G_DIM;
      uint32_t wb[16];
      #pragma unroll
      for (int q = 0; q < 8; ++q) {
        float4 v = ((const float4*)src)[q];
        wb[2*q]   = pack2bf16(v.x * sf, v.y * sf);
        wb[2*q+1] = pack2bf16(v.z * sf, v.w * sf);
      }
      ((uint4*)Brow)[0] = make_uint4(wb[0],  wb[1],  wb[2],  wb[3]);
      ((uint4*)Brow)[1] = make_uint4(wb[4],  wb[5],  wb[6],  wb[7]);
      ((uint4*)Brow)[2] = make_uint4(wb[8],  wb[9],  wb[10], wb[11]);
      ((uint4*)Brow)[3] = make_uint4(wb[12], wb[13], wb[14], wb[15]);
    }

    __syncthreads();

    // ---- MFMA: 2 k-steps x 4x4 tiles = 32 MFMA / wave / iter
    #pragma unroll
    for (int ks = 0; ks < 2; ++ks) {
      s8v a[4], b[4];
      #pragma unroll
      for (int tm = 0; tm < 4; ++tm)
        a[tm] = *(const s8v*)&A_lds[(wm * 64 + tm * 16 + l15) * PITCH + ks * 32 + kgrp];
      #pragma unroll
      for (int tn = 0; tn < 4; ++tn)
        b[tn] = *(const s8v*)&B_lds[(wn * 64 + tn * 16 + l15) * PITCH + ks * 32 + kgrp];
      #pragma unroll
      for (int tm = 0; tm < 4; ++tm)
        #pragma unroll
        for (int tn = 0; tn < 4; ++tn)
          acc[tm][tn] = __builtin_amdgcn_mfma_f32_16x16x32_bf16(a[tm], b[tn], acc[tm][tn], 0, 0, 0);
    }
  }

  // ---------------- base tile: K=32 (16 silu features + 16 zeros), single k-step
  __syncthreads();
  {
    // A: silu(x) at t = i_local; thread covers t = half*8 .. +8, zeros at t in [16,32)
    const float* xb = xrow + half * 8;
    float4 v0 = ((const float4*)xb)[0];
    float4 v1 = ((const float4*)xb)[1];
    uint32_t a0 = pack2bf16(silu_f(v0.x), silu_f(v0.y));
    uint32_t a1 = pack2bf16(silu_f(v0.z), silu_f(v0.w));
    uint32_t a2 = pack2bf16(silu_f(v1.x), silu_f(v1.y));
    uint32_t a3 = pack2bf16(silu_f(v1.z), silu_f(v1.w));
    ((uint4*)&A_lds[row * PITCH + half * 8])[0]      = make_uint4(a0, a1, a2, a3);
    ((uint4*)&A_lds[row * PITCH + 16 + half * 8])[0] = make_uint4(0, 0, 0, 0);

    // B: scale_base*mask at t = i_local
    uint32_t w[4];
    #pragma unroll
    for (int p = 0; p < 4; ++p) {
      const int ia = i0 + half * 8 + 2 * p;
      const size_t o0 = (size_t)ia * O_DIM + jg;
      const size_t o1 = o0 + O_DIM;
      w[p] = pack2bf16(scale_base[o0] * mask[o0], scale_base[o1] * mask[o1]);
    }
    ((uint4*)&B_lds[row * PITCH + half * 8])[0]      = make_uint4(w[0], w[1], w[2], w[3]);
    ((uint4*)&B_lds[row * PITCH + 16 + half * 8])[0] = make_uint4(0, 0, 0, 0);
  }
  __syncthreads();
  {
    s8v a[4], b[4];
    #pragma unroll
    for (int tm = 0; tm < 4; ++tm)
      a[tm] = *(const s8v*)&A_lds[(wm * 64 + tm * 16 + l15) * PITCH + kgrp];
    #pragma unroll
    for (int tn = 0; tn < 4; ++tn)
      b[tn] = *(const s8v*)&B_lds[(wn * 64 + tn * 16 + l15) * PITCH + kgrp];
    #pragma unroll
    for (int tm = 0; tm < 4; ++tm)
      #pragma unroll
      for (int tn = 0; tn < 4; ++tn)
        acc[tm][tn] = __builtin_amdgcn_mfma_f32_16x16x32_bf16(a[tm], b[tn], acc[tm][tn], 0, 0, 0);
  }

  // ---------------- epilogue: C/D layout col=lane&15, row=quad*4+reg (validated R1)
  const int quad = lane >> 4;
  #pragma unroll
  for (int tm = 0; tm < 4; ++tm) {
    #pragma unroll
    for (int tn = 0; tn < 4; ++tn) {
      const int n_g = bn * BN + wn * 64 + tn * 16 + l15;
      f4v v = acc[tm][tn];
      #pragma unroll
      for (int r = 0; r < 4; ++r) {
        const int m_g = bm * BM + wm * 64 + tm * 16 + quad * 4 + r;
        float val = v[r];
        if (kc == 0) val += bias[n_g];
        atomicAdd(&out[(size_t)m_g * O_DIM + n_g], val);
      }
    }
  }
}

extern "C" void kernel_launch(void* const* d_in, const int* in_sizes, int n_in,
                              void* d_out, int out_size, void* d_ws, size_t ws_size,
                              hipStream_t stream) {
  const float* x          = (const float*)d_in[0];
  const float* fc         = (const float*)d_in[1];
  const float* bias       = (const float*)d_in[2];
  const float* mask       = (const float*)d_in[3];
  const float* scale_base = (const float*)d_in[4];
  const float* scale_fft  = (const float*)d_in[5];
  float* out = (float*)d_out;

  hipMemsetAsync(d_out, 0, (size_t)out_size * sizeof(float), stream);

  // grid: kc(16) x bn(2) x bm(32) = 1024 blocks = 4 per CU
  kan_fft_kernel<<<dim3(1024), dim3(256), 0, stream>>>(
      x, fc, bias, mask, scale_base, scale_fft, out);
}

// Round 3
// 184.260 us; speedup vs baseline: 1.1634x; 1.0927x over previous
//
#include <hip/hip_runtime.h>
#include <stdint.h>

// out[b,j] = bias[j] + sum_i [ mask*scale_base[i,j]*silu(x[b,i])
//            + mask*scale_fft[i,j]* sum_k ( cos(k*x)*fc0[j,i,k] + sin(k*x)*fc1[j,i,k] ) ]
// GEMM view: M=4096, N=256, K=256*65. bf16 MFMA 16x16x32.
// R3: (1) split-K partials to d_ws + reduce kernel (no cross-XCD atomics),
//     (2) prep kernel pre-packs B (fc*scale_fft*mask -> bf16) so hot-loop B
//         staging is a pure prefetched copy. Atomic fallback if ws too small.

#define I_DIM 256
#define O_DIM 256
#define G_DIM 32
#define B_DIM 4096

#define BM 128
#define BN 128
#define KSPLIT 16
#define ICH 16                  // i's per K-chunk
#define PITCH 72                // shorts per LDS row (64 + 8 pad; 144 B stride)

typedef short s8v __attribute__((ext_vector_type(8)));   // 8 bf16
typedef float f4v __attribute__((ext_vector_type(4)));   // 4 f32 acc

__device__ __forceinline__ uint32_t pack2bf16(float a, float b) {
  uint32_t ua = __builtin_bit_cast(uint32_t, a);
  uint32_t ub = __builtin_bit_cast(uint32_t, b);
  ua += 0x7FFFu + ((ua >> 16) & 1u);     // RNE
  ub += 0x7FFFu + ((ub >> 16) & 1u);
  return (ua >> 16) | (ub & 0xFFFF0000u);
}

__device__ __forceinline__ float silu_f(float v) {
  return v / (1.0f + __expf(-v));
}

// ---------------------------------------------------------------- prep: pack B
// Bp[j*256+i][t] (bf16): t<32 -> fc0[j,i,t]*sf ; t>=32 -> fc1[j,i,t-32]*sf
__global__ __launch_bounds__(256) void prep_b_kernel(
    const float* __restrict__ fc, const float* __restrict__ mask,
    const float* __restrict__ sfft, short* __restrict__ Bp)
{
  const int gid = blockIdx.x * 256 + threadIdx.x;  // 0..131071
  const int p = gid >> 1, d = gid & 1;
  const int j = p >> 8, i = p & 255;
  const float sf = sfft[i * O_DIM + j] * mask[i * O_DIM + j];
  const float* src = fc + (((size_t)d * O_DIM + j) * I_DIM + i) * G_DIM;
  uint32_t wb[16];
  #pragma unroll
  for (int q = 0; q < 8; ++q) {
    float4 v = ((const float4*)src)[q];
    wb[2*q]   = pack2bf16(v.x * sf, v.y * sf);
    wb[2*q+1] = pack2bf16(v.z * sf, v.w * sf);
  }
  uint4* dst = (uint4*)(Bp + (size_t)p * 64 + d * 32);
  dst[0] = make_uint4(wb[0],  wb[1],  wb[2],  wb[3]);
  dst[1] = make_uint4(wb[4],  wb[5],  wb[6],  wb[7]);
  dst[2] = make_uint4(wb[8],  wb[9],  wb[10], wb[11]);
  dst[3] = make_uint4(wb[12], wb[13], wb[14], wb[15]);
}

// ---------------------------------------------------------------- main GEMM
__global__ __launch_bounds__(256, 4) void kan_main(
    const float* __restrict__ x,
    const short* __restrict__ Bp,
    const float* __restrict__ mask,
    const float* __restrict__ scale_base,
    float* __restrict__ partial)          // (KSPLIT, 4096, 256) f32
{
  __shared__ short A_lds[BM * PITCH];
  __shared__ short B_lds[BN * PITCH];

  const int tid = threadIdx.x;
  const int bx  = blockIdx.x;
  const int kc  = bx & 15;
  const int bn  = (bx >> 4) & 1;
  const int bm  = bx >> 5;
  const int i0  = kc * ICH;

  const int lane = tid & 63;
  const int wave = tid >> 6;
  const int wm   = wave & 1;
  const int wn   = wave >> 1;
  const int l15  = lane & 15;
  const int kgrp = (lane >> 4) * 8;

  f4v acc[4][4];
  #pragma unroll
  for (int a = 0; a < 4; ++a)
    #pragma unroll
    for (int b = 0; b < 4; ++b)
      acc[a][b] = (f4v){0.f, 0.f, 0.f, 0.f};

  const int row  = tid >> 1;
  const int half = tid & 1;
  const int mg   = bm * BM + row;
  const int jg   = bn * BN + row;

  const float* xrow = x + (size_t)mg * I_DIM + i0;
  const short* bsrc = Bp + ((size_t)jg * I_DIM + i0) * 64 + half * 32;
  uint32_t* Arow = (uint32_t*)&A_lds[row * PITCH + half * 32];
  uint4*    Brow = (uint4*)&B_lds[row * PITCH + half * 32];

  // prefetch B for it=0
  uint4 bpre[4];
  #pragma unroll
  for (int q = 0; q < 4; ++q) bpre[q] = ((const uint4*)bsrc)[q];

  for (int it = 0; it < ICH; ++it) {
    __syncthreads();                      // prior MFMA reads done

    // ---- B: store prefetched regs, then issue next iter's loads
    Brow[0] = bpre[0]; Brow[1] = bpre[1]; Brow[2] = bpre[2]; Brow[3] = bpre[3];
    if (it + 1 < ICH) {
      const uint4* nb = (const uint4*)(bsrc + (size_t)(it + 1) * 64);
      #pragma unroll
      for (int q = 0; q < 4; ++q) bpre[q] = nb[q];
    }

    // ---- A: Chebyshev, f_{k+1} = 2c*f_k - f_{k-1}; half=0 cos, half=1 sin
    {
      const float xv = xrow[it];
      float s, c;
      __sincosf(xv, &s, &c);
      const float m2 = 2.f * c;
      float f0 = half ? s : c;
      float f1 = m2 * f0 - (half ? 0.f : 1.f);
      uint32_t fb[16];
      fb[0] = pack2bf16(f0, f1);
      #pragma unroll
      for (int p = 1; p < 16; ++p) {
        float f2 = m2 * f1 - f0;
        float f3 = m2 * f2 - f1;
        fb[p] = pack2bf16(f2, f3);
        f0 = f2; f1 = f3;
      }
      ((uint4*)Arow)[0] = make_uint4(fb[0],  fb[1],  fb[2],  fb[3]);
      ((uint4*)Arow)[1] = make_uint4(fb[4],  fb[5],  fb[6],  fb[7]);
      ((uint4*)Arow)[2] = make_uint4(fb[8],  fb[9],  fb[10], fb[11]);
      ((uint4*)Arow)[3] = make_uint4(fb[12], fb[13], fb[14], fb[15]);
    }

    __syncthreads();

    #pragma unroll
    for (int ks = 0; ks < 2; ++ks) {
      s8v a[4], b[4];
      #pragma unroll
      for (int tm = 0; tm < 4; ++tm)
        a[tm] = *(const s8v*)&A_lds[(wm * 64 + tm * 16 + l15) * PITCH + ks * 32 + kgrp];
      #pragma unroll
      for (int tn = 0; tn < 4; ++tn)
        b[tn] = *(const s8v*)&B_lds[(wn * 64 + tn * 16 + l15) * PITCH + ks * 32 + kgrp];
      #pragma unroll
      for (int tm = 0; tm < 4; ++tm)
        #pragma unroll
        for (int tn = 0; tn < 4; ++tn)
          acc[tm][tn] = __builtin_amdgcn_mfma_f32_16x16x32_bf16(a[tm], b[tn], acc[tm][tn], 0, 0, 0);
    }
  }

  // ---------------- base tile: K=32 (16 silu features + 16 zeros)
  __syncthreads();
  {
    const float* xb = xrow + half * 8;
    float4 v0 = ((const float4*)xb)[0];
    float4 v1 = ((const float4*)xb)[1];
    uint32_t a0 = pack2bf16(silu_f(v0.x), silu_f(v0.y));
    uint32_t a1 = pack2bf16(silu_f(v0.z), silu_f(v0.w));
    uint32_t a2 = pack2bf16(silu_f(v1.x), silu_f(v1.y));
    uint32_t a3 = pack2bf16(silu_f(v1.z), silu_f(v1.w));
    ((uint4*)&A_lds[row * PITCH + half * 8])[0]      = make_uint4(a0, a1, a2, a3);
    ((uint4*)&A_lds[row * PITCH + 16 + half * 8])[0] = make_uint4(0, 0, 0, 0);

    uint32_t w[4];
    #pragma unroll
    for (int p = 0; p < 4; ++p) {
      const int ia = i0 + half * 8 + 2 * p;
      const size_t o0 = (size_t)ia * O_DIM + jg;
      const size_t o1 = o0 + O_DIM;
      w[p] = pack2bf16(scale_base[o0] * mask[o0], scale_base[o1] * mask[o1]);
    }
    ((uint4*)&B_lds[row * PITCH + half * 8])[0]      = make_uint4(w[0], w[1], w[2], w[3]);
    ((uint4*)&B_lds[row * PITCH + 16 + half * 8])[0] = make_uint4(0, 0, 0, 0);
  }
  __syncthreads();
  {
    s8v a[4], b[4];
    #pragma unroll
    for (int tm = 0; tm < 4; ++tm)
      a[tm] = *(const s8v*)&A_lds[(wm * 64 + tm * 16 + l15) * PITCH + kgrp];
    #pragma unroll
    for (int tn = 0; tn < 4; ++tn)
      b[tn] = *(const s8v*)&B_lds[(wn * 64 + tn * 16 + l15) * PITCH + kgrp];
    #pragma unroll
    for (int tm = 0; tm < 4; ++tm)
      #pragma unroll
      for (int tn = 0; tn < 4; ++tn)
        acc[tm][tn] = __builtin_amdgcn_mfma_f32_16x16x32_bf16(a[tm], b[tn], acc[tm][tn], 0, 0, 0);
  }

  // ---------------- epilogue: coalesced partial stores (no atomics)
  float* pbase = partial + (size_t)kc * B_DIM * O_DIM;
  const int quad = lane >> 4;
  #pragma unroll
  for (int tm = 0; tm < 4; ++tm) {
    #pragma unroll
    for (int tn = 0; tn < 4; ++tn) {
      const int n_g = bn * BN + wn * 64 + tn * 16 + l15;
      f4v v = acc[tm][tn];
      #pragma unroll
      for (int r = 0; r < 4; ++r) {
        const int m_g = bm * BM + wm * 64 + tm * 16 + quad * 4 + r;
        pbase[(size_t)m_g * O_DIM + n_g] = v[r];
      }
    }
  }
}

// ---------------------------------------------------------------- reduce
__global__ __launch_bounds__(256) void reduce_kernel(
    const float* __restrict__ partial, const float* __restrict__ bias,
    float* __restrict__ out)
{
  const int g  = blockIdx.x * 256 + threadIdx.x;   // 0..262143
  const int m  = g >> 6;
  const int n4 = (g & 63) << 2;
  float4 acc = ((const float4*)(bias + n4))[0];
  #pragma unroll
  for (int kc = 0; kc < KSPLIT; ++kc) {
    float4 v = ((const float4*)(partial + ((size_t)kc * B_DIM + m) * O_DIM + n4))[0];
    acc.x += v.x; acc.y += v.y; acc.z += v.z; acc.w += v.w;
  }
  ((float4*)(out + (size_t)m * O_DIM + n4))[0] = acc;
}

// ---------------------------------------------------------------- fallback (R2)
__global__ __launch_bounds__(256, 4) void kan_fft_fallback(
    const float* __restrict__ x, const float* __restrict__ fc,
    const float* __restrict__ bias, const float* __restrict__ mask,
    const float* __restrict__ scale_base, const float* __restrict__ scale_fft,
    float* __restrict__ out)
{
  __shared__ short A_lds[BM * PITCH];
  __shared__ short B_lds[BN * PITCH];

  const int tid = threadIdx.x;
  const int bx  = blockIdx.x;
  const int kc  = bx & 15;
  const int bn  = (bx >> 4) & 1;
  const int bm  = bx >> 5;
  const int i0  = kc * ICH;

  const int lane = tid & 63;
  const int wave = tid >> 6;
  const int wm   = wave & 1;
  const int wn   = wave >> 1;
  const int l15  = lane & 15;
  const int kgrp = (lane >> 4) * 8;

  f4v acc[4][4];
  #pragma unroll
  for (int a = 0; a < 4; ++a)
    #pragma unroll
    for (int b = 0; b < 4; ++b)
      acc[a][b] = (f4v){0.f, 0.f, 0.f, 0.f};

  const int row  = tid >> 1;
  const int half = tid & 1;
  const int mg   = bm * BM + row;
  const int jg   = bn * BN + row;

  const float* xrow   = x + (size_t)mg * I_DIM + i0;
  const float* fcbase = fc + (size_t)half * (O_DIM * I_DIM * G_DIM)
                           + ((size_t)jg * I_DIM + i0) * G_DIM;
  uint32_t* Arow = (uint32_t*)&A_lds[row * PITCH + half * 32];
  uint32_t* Brow = (uint32_t*)&B_lds[row * PITCH + half * 32];

  for (int it = 0; it < ICH; ++it) {
    __syncthreads();
    {
      const float xv = xrow[it];
      float s, c;
      __sincosf(xv, &s, &c);
      const float m2 = 2.f * c;
      float f0 = half ? s : c;
      float f1 = m2 * f0 - (half ? 0.f : 1.f);
      uint32_t fb[16];
      fb[0] = pack2bf16(f0, f1);
      #pragma unroll
      for (int p = 1; p < 16; ++p) {
        float f2 = m2 * f1 - f0;
        float f3 = m2 * f2 - f1;
        fb[p] = pack2bf16(f2, f3);
        f0 = f2; f1 = f3;
      }
      ((uint4*)Arow)[0] = make_uint4(fb[0],  fb[1],  fb[2],  fb[3]);
      ((uint4*)Arow)[1] = make_uint4(fb[4],  fb[5],  fb[6],  fb[7]);
      ((uint4*)Arow)[2] = make_uint4(fb[8],  fb[9],  fb[10], fb[11]);
      ((uint4*)Arow)[3] = make_uint4(fb[12], fb[13], fb[14], fb[15]);
    }
    {
      const int i = i0 + it;
      const size_t ij = (size_t)i * O_DIM + jg;
      const float sf  = scale_fft[ij] * mask[ij];
      const float* src = fcbase + it * G_DIM;
      uint32_t wb[16];
      #pragma unroll
      for (int q = 0; q < 8; ++q) {
        float4 v = ((const float4*)src)[q];
        wb[2*q]   = pack2bf16(v.x * sf, v.y * sf);
        wb[2*q+1] = pack2bf16(v.z * sf, v.w * sf);
      }
      ((uint4*)Brow)[0] = make_uint4(wb[0],  wb[1],  wb[2],  wb[3]);
      ((uint4*)Brow)[1] = make_uint4(wb[4],  wb[5],  wb[6],  wb[7]);
      ((uint4*)Brow)[2] = make_uint4(wb[8],  wb[9],  wb[10], wb[11]);
      ((uint4*)Brow)[3] = make_uint4(wb[12], wb[13], wb[14], wb[15]);
    }
    __syncthreads();
    #pragma unroll
    for (int ks = 0; ks < 2; ++ks) {
      s8v a[4], b[4];
      #pragma unroll
      for (int tm = 0; tm < 4; ++tm)
        a[tm] = *(const s8v*)&A_lds[(wm * 64 + tm * 16 + l15) * PITCH + ks * 32 + kgrp];
      #pragma unroll
      for (int tn = 0; tn < 4; ++tn)
        b[tn] = *(const s8v*)&B_lds[(wn * 64 + tn * 16 + l15) * PITCH + ks * 32 + kgrp];
      #pragma unroll
      for (int tm = 0; tm < 4; ++tm)
        #pragma unroll
        for (int tn = 0; tn < 4; ++tn)
          acc[tm][tn] = __builtin_amdgcn_mfma_f32_16x16x32_bf16(a[tm], b[tn], acc[tm][tn], 0, 0, 0);
    }
  }

  __syncthreads();
  {
    const float* xb = xrow + half * 8;
    float4 v0 = ((const float4*)xb)[0];
    float4 v1 = ((const float4*)xb)[1];
    uint32_t a0 = pack2bf16(silu_f(v0.x), silu_f(v0.y));
    uint32_t a1 = pack2bf16(silu_f(v0.z), silu_f(v0.w));
    uint32_t a2 = pack2bf16(silu_f(v1.x), silu_f(v1.y));
    uint32_t a3 = pack2bf16(silu_f(v1.z), silu_f(v1.w));
    ((uint4*)&A_lds[row * PITCH + half * 8])[0]      = make_uint4(a0, a1, a2, a3);
    ((uint4*)&A_lds[row * PITCH + 16 + half * 8])[0] = make_uint4(0, 0, 0, 0);
    uint32_t w[4];
    #pragma unroll
    for (int p = 0; p < 4; ++p) {
      const int ia = i0 + half * 8 + 2 * p;
      const size_t o0 = (size_t)ia * O_DIM + jg;
      const size_t o1 = o0 + O_DIM;
      w[p] = pack2bf16(scale_base[o0] * mask[o0], scale_base[o1] * mask[o1]);
    }
    ((uint4*)&B_lds[row * PITCH + half * 8])[0]      = make_uint4(w[0], w[1], w[2], w[3]);
    ((uint4*)&B_lds[row * PITCH + 16 + half * 8])[0] = make_uint4(0, 0, 0, 0);
  }
  __syncthreads();
  {
    s8v a[4], b[4];
    #pragma unroll
    for (int tm = 0; tm < 4; ++tm)
      a[tm] = *(const s8v*)&A_lds[(wm * 64 + tm * 16 + l15) * PITCH + kgrp];
    #pragma unroll
    for (int tn = 0; tn < 4; ++tn)
      b[tn] = *(const s8v*)&B_lds[(wn * 64 + tn * 16 + l15) * PITCH + kgrp];
    #pragma unroll
    for (int tm = 0; tm < 4; ++tm)
      #pragma unroll
      for (int tn = 0; tn < 4; ++tn)
        acc[tm][tn] = __builtin_amdgcn_mfma_f32_16x16x32_bf16(a[tm], b[tn], acc[tm][tn], 0, 0, 0);
  }

  const int quad = lane >> 4;
  #pragma unroll
  for (int tm = 0; tm < 4; ++tm) {
    #pragma unroll
    for (int tn = 0; tn < 4; ++tn) {
      const int n_g = bn * BN + wn * 64 + tn * 16 + l15;
      f4v v = acc[tm][tn];
      #pragma unroll
      for (int r = 0; r < 4; ++r) {
        const int m_g = bm * BM + wm * 64 + tm * 16 + quad * 4 + r;
        float val = v[r];
        if (kc == 0) val += bias[n_g];
        atomicAdd(&out[(size_t)m_g * O_DIM + n_g], val);
      }
    }
  }
}

extern "C" void kernel_launch(void* const* d_in, const int* in_sizes, int n_in,
                              void* d_out, int out_size, void* d_ws, size_t ws_size,
                              hipStream_t stream) {
  const float* x          = (const float*)d_in[0];
  const float* fc         = (const float*)d_in[1];
  const float* bias       = (const float*)d_in[2];
  const float* mask       = (const float*)d_in[3];
  const float* scale_base = (const float*)d_in[4];
  const float* scale_fft  = (const float*)d_in[5];
  float* out = (float*)d_out;

  const size_t BP_BYTES   = (size_t)O_DIM * I_DIM * 64 * 2;           // 8.4 MB
  const size_t PART_BYTES = (size_t)KSPLIT * B_DIM * O_DIM * 4;       // 67.1 MB
  if (ws_size >= BP_BYTES + PART_BYTES) {
    short* Bp      = (short*)d_ws;
    float* partial = (float*)((char*)d_ws + BP_BYTES);
    prep_b_kernel<<<dim3(512), dim3(256), 0, stream>>>(fc, mask, scale_fft, Bp);
    kan_main<<<dim3(1024), dim3(256), 0, stream>>>(x, Bp, mask, scale_base, partial);
    reduce_kernel<<<dim3(1024), dim3(256), 0, stream>>>(partial, bias, out);
  } else {
    hipMemsetAsync(d_out, 0, (size_t)out_size * sizeof(float), stream);
    kan_fft_fallback<<<dim3(1024), dim3(256), 0, stream>>>(
        x, fc, bias, mask, scale_base, scale_fft, out);
  }
}